// Round 6
// baseline (83.082 us; speedup 1.0000x reference)
//
#include <hip/hip_runtime.h>
#include <hip/hip_bf16.h>

#define B_   8
#define H_   256
#define L_   4096
#define N2_  32

typedef __attribute__((ext_vector_type(8))) short bf16x8;
typedef __attribute__((ext_vector_type(4))) float f32x4;

__device__ __forceinline__ unsigned short f2bf(float x) {
    __hip_bfloat16 h = __float2bfloat16(x);
    unsigned short us;
    __builtin_memcpy(&us, &h, 2);
    return us;
}

union BF8 { ushort4 u4[2]; unsigned short s[8]; bf16x8 v; };

__device__ __forceinline__ float gelu_exact(float y) {
    return 0.5f * y * (1.0f + erff(y * 0.70710678118654752440f));
}

// hw sin/cos with explicit revolution reduction (v_sin_f32 takes revolutions)
__device__ __forceinline__ void fast_sincos(float x, float* s, float* c) {
    float rev = x * 0.15915494309189535f;
    rev = rev - floorf(rev);
    *s = __builtin_amdgcn_sinf(rev);
    *c = __builtin_amdgcn_cosf(rev);
}

// ---------------------------------------------------------------------------
// Kernel 0 (prep): blocks 0..255 = one head each (256 thr): build P, Tk
// (with D folded into taps[0]: conv(k,u)+D*u = conv(k+D*delta0, u)), Q.
// Blocks 256..383: W -> bf16 swizzled.
// ---------------------------------------------------------------------------
__global__ __launch_bounds__(256) void prep_kernel(
    const float* __restrict__ log_dt,
    const float* __restrict__ log_A_real,
    const float* __restrict__ A_imag,
    const float* __restrict__ C_re,
    const float* __restrict__ C_im,
    const float* __restrict__ Dp,
    const float* __restrict__ W,
    unsigned short* __restrict__ MAT,
    unsigned short* __restrict__ W2)
{
    const int bid = blockIdx.x;
    const int tid = threadIdx.x;
    if (bid >= 256) {
        int gq = (bid - 256) * 256 + tid;        // 0..32767
        int m = gq >> 6, t = gq & 63;
        int ks = t >> 4, sub = t & 15;
        int gr = sub >> 1, e4 = (sub & 1) * 4;
        int klog = ks * 64 + ((gr ^ (m & 7)) << 3) + e4;
        float4 wv = *(const float4*)&W[m * 256 + klog];
        ushort4 o;
        o.x = f2bf(wv.x); o.y = f2bf(wv.y); o.z = f2bf(wv.z); o.w = f2bf(wv.w);
        *(ushort4*)&W2[ks * 32768 + m * 64 + gr * 8 + e4] = o;
        return;
    }
    const int h    = bid;
    const int j    = tid & 63;
    const int part = tid >> 6;                   // 0..3 -> 8 n's each

    __shared__ float sAr[32], sAi[32], sK2r[32], sK2i[32];
    __shared__ float sTap[4][64];
    __shared__ unsigned short sQ[64 * 68];

    unsigned short* __restrict__ Pd  = MAT + (size_t)h * 12288;
    unsigned short* __restrict__ Tkd = Pd + 4096;
    unsigned short* __restrict__ Qd  = Pd + 8192;
    const float dt = __expf(log_dt[h]);

    if (tid < 32) {
        int n = tid;
        float Ar = -__expf(log_A_real[h * 32 + n]);
        float Ai = A_imag[h * 32 + n];
        float er = __expf(dt * Ar);
        float s, c; fast_sincos(dt * Ai, &s, &c);
        float wr = er * c, wi = er * s;
        float Cr = C_re[h * 32 + n], Ci = C_im[h * 32 + n];
        float den = Ar * Ar + Ai * Ai;
        float nr = wr - 1.0f, ni = wi;
        float qr = (nr * Ar + ni * Ai) / den;
        float qi = (ni * Ar - nr * Ai) / den;
        sAr[n] = Ar; sAi[n] = Ai;
        sK2r[n] = 2.0f * (Cr * qr - Ci * qi);
        sK2i[n] = 2.0f * (Cr * qi + Ci * qr);
    }
    __syncthreads();

    // ---- P[2n][j] = Re(w_n^{63-j}), P[2n+1][j] = Im ----
    {
        float pdt = dt * (float)(63 - j);
        #pragma unroll
        for (int q = 0; q < 8; ++q) {
            int n = part * 8 + q;
            float mag = __expf(pdt * sAr[n]);
            float s, c; fast_sincos(pdt * sAi[n], &s, &c);
            Pd[(2 * n)     * 64 + j] = f2bf(mag * c);
            Pd[(2 * n + 1) * 64 + j] = f2bf(mag * s);
        }
    }
    // ---- taps partial sums + Q staging ----
    {
        float jdt = dt * (float)j;
        float acc = 0.0f;
        #pragma unroll
        for (int q = 0; q < 8; ++q) {
            int n = part * 8 + q;
            float mag = __expf(jdt * sAr[n]);
            float s, c; fast_sincos(jdt * sAi[n], &s, &c);
            acc = fmaf(sK2r[n], mag * c, fmaf(-sK2i[n], mag * s, acc));
        }
        sTap[part][j] = acc;
        float j1dt = dt * (float)(j + 1);
        #pragma unroll
        for (int q = 0; q < 8; ++q) {
            int n = part * 8 + q;
            float mag = __expf(j1dt * sAr[n]);
            float s, c; fast_sincos(j1dt * sAi[n], &s, &c);
            float wpr = mag * c, wpi = mag * s;
            sQ[j * 68 + 2 * n]     = f2bf(sK2r[n] * wpr - sK2i[n] * wpi);
            sQ[j * 68 + 2 * n + 1] = f2bf(-(sK2r[n] * wpi + sK2i[n] * wpr));
        }
    }
    __syncthreads();
    if (part == 0) {
        float v = sTap[0][j] + sTap[1][j] + sTap[2][j] + sTap[3][j];
        if (j == 0) v += Dp[h];                  // fold D-skip into tap 0
        sTap[0][j] = v;
    }
    __syncthreads();

    // ---- Tk[r][c] = taps[r-c] (r>=c) ----
    {
        int r  = tid >> 2;
        int c0 = (tid & 3) * 16;
        #pragma unroll
        for (int cc = 0; cc < 16; cc += 4) {
            int c = c0 + cc;
            ushort4 v;
            v.x = (r - c     >= 0) ? f2bf(sTap[0][r - c])     : (unsigned short)0;
            v.y = (r - c - 1 >= 0) ? f2bf(sTap[0][r - c - 1]) : (unsigned short)0;
            v.z = (r - c - 2 >= 0) ? f2bf(sTap[0][r - c - 2]) : (unsigned short)0;
            v.w = (r - c - 3 >= 0) ? f2bf(sTap[0][r - c - 3]) : (unsigned short)0;
            *(ushort4*)&Tkd[r * 64 + c] = v;
        }
    }
    // ---- Q cooperative coalesced store ----
    #pragma unroll
    for (int it = 0; it < 4; ++it) {
        int quad = it * 256 + tid;
        int row = quad >> 4, c4 = (quad & 15) * 4;
        ushort4 v;
        v.x = sQ[row * 68 + c4];     v.y = sQ[row * 68 + c4 + 1];
        v.z = sQ[row * 68 + c4 + 2]; v.w = sQ[row * 68 + c4 + 3];
        *(ushort4*)&Qd[row * 64 + c4] = v;
    }
}

// ---------------------------------------------------------------------------
// Kernel 1: MFMA-based chunked scan. D folded into Tk -> no u re-read.
// Output layout G[b][l6][hg][col][4h] (32 KB contiguous per (b,l6) slice).
// ---------------------------------------------------------------------------
__global__ __launch_bounds__(256, 2) void s4_mfma_kernel(
    const float* __restrict__ u,
    const float* __restrict__ log_dt,
    const float* __restrict__ log_A_real,
    const float* __restrict__ A_imag,
    const unsigned short* __restrict__ MAT,
    unsigned short* __restrict__ Gout)
{
    __shared__ __align__(16) unsigned char smem[4 * 17408];   // 68 KB
    const int tid  = threadIdx.x;
    const int w    = tid >> 6;
    const int lane = tid & 63;
    const int ln15 = lane & 15;
    const int hi4  = (lane >> 4) * 4;
    const int hi8  = (lane >> 4) * 8;
    const int bid  = blockIdx.x;
    const int b    = bid >> 6, hg = bid & 63;
    const int h    = hg * 4 + w;

    float* Eb = (float*)(smem + w * 17408);                    // [c][68] fp32
    unsigned short* yb = (unsigned short*)(smem + w * 17408);  // bf16 overlay

    const float* __restrict__ urow = u + ((size_t)(b * H_ + h)) * L_;
    const unsigned short* __restrict__ Ph  = MAT + (size_t)h * 12288;
    const unsigned short* __restrict__ Tkh = Ph + 4096;
    const unsigned short* __restrict__ Qh  = Ph + 8192;

    // w^64 for the serial scan
    float wTr, wTi;
    {
        int n = lane & 31;
        float dt = expf(log_dt[h]);
        float Ar = -expf(log_A_real[h * 32 + n]);
        float Ai = A_imag[h * 32 + n];
        float er = expf(dt * Ar); float s, c; sincosf(dt * Ai, &s, &c);
        float pr = er * c, pi = er * s;
        #pragma unroll
        for (int k = 0; k < 6; ++k) { float a2 = pr*pr - pi*pi, b2 = 2.0f*pr*pi; pr = a2; pi = b2; }
        wTr = pr; wTi = pi;
    }

    // ---- Phase A: U fragments (kept for phase C) + E = P*U ----
    bf16x8 ufr[4][2];
    #pragma unroll
    for (int nt = 0; nt < 4; ++nt) {
        int c = nt * 16 + ln15;
        #pragma unroll
        for (int ks = 0; ks < 2; ++ks) {
            const float* p = urow + c * 64 + ks * 32 + hi8;
            float4 lo = *(const float4*)p;
            float4 hi = *(const float4*)(p + 4);
            BF8 t8;
            t8.s[0]=f2bf(lo.x); t8.s[1]=f2bf(lo.y); t8.s[2]=f2bf(lo.z); t8.s[3]=f2bf(lo.w);
            t8.s[4]=f2bf(hi.x); t8.s[5]=f2bf(hi.y); t8.s[6]=f2bf(hi.z); t8.s[7]=f2bf(hi.w);
            ufr[nt][ks] = t8.v;
        }
    }
    #pragma unroll
    for (int mt = 0; mt < 4; ++mt) {
        bf16x8 pa[2];
        #pragma unroll
        for (int ks = 0; ks < 2; ++ks)
            pa[ks] = *(const bf16x8*)&Ph[(mt * 16 + ln15) * 64 + ks * 32 + hi8];
        f32x4 e[4];
        #pragma unroll
        for (int nt = 0; nt < 4; ++nt) e[nt] = (f32x4){0.f, 0.f, 0.f, 0.f};
        #pragma unroll
        for (int ks = 0; ks < 2; ++ks)
            #pragma unroll
            for (int nt = 0; nt < 4; ++nt)
                e[nt] = __builtin_amdgcn_mfma_f32_16x16x32_bf16(pa[ks], ufr[nt][ks], e[nt], 0, 0, 0);
        #pragma unroll
        for (int nt = 0; nt < 4; ++nt)
            *(f32x4*)&Eb[(nt * 16 + ln15) * 68 + mt * 16 + hi4] = e[nt];
    }
    __syncthreads();

    // ---- Phase B: serial scan over 64 chunks; leaves INCOMING state S[c] ----
    if (lane < 32) {
        int n2 = 2 * lane;
        float Xr = 0.0f, Xi = 0.0f;
        float2 e = *(float2*)&Eb[n2];
        #pragma unroll 4
        for (int c = 0; c < 64; ++c) {
            float2 en = e;
            if (c < 63) en = *(float2*)&Eb[(c + 1) * 68 + n2];
            *(float2*)&Eb[c * 68 + n2] = make_float2(Xr, Xi);
            float nXr = fmaf(wTr, Xr, fmaf(-wTi, Xi, e.x));
            float nXi = fmaf(wTi, Xr, fmaf( wTr, Xi, e.y));
            Xr = nXr; Xi = nXi; e = en;
        }
    }
    __syncthreads();

    // ---- Phase C: Y = Tk*U + Q*S (D folded in Tk), GELU, bf16 ----
    bf16x8 sfr[4][2];
    #pragma unroll
    for (int nt = 0; nt < 4; ++nt) {
        int c = nt * 16 + ln15;
        #pragma unroll
        for (int ks = 0; ks < 2; ++ks) {
            float4 lo = *(const float4*)&Eb[c * 68 + ks * 32 + hi8];
            float4 hi = *(const float4*)&Eb[c * 68 + ks * 32 + hi8 + 4];
            BF8 t8;
            t8.s[0]=f2bf(lo.x); t8.s[1]=f2bf(lo.y); t8.s[2]=f2bf(lo.z); t8.s[3]=f2bf(lo.w);
            t8.s[4]=f2bf(hi.x); t8.s[5]=f2bf(hi.y); t8.s[6]=f2bf(hi.z); t8.s[7]=f2bf(hi.w);
            sfr[nt][ks] = t8.v;
        }
    }
    #pragma unroll
    for (int mt = 0; mt < 4; ++mt) {
        bf16x8 ta[2], qa[2];
        #pragma unroll
        for (int ks = 0; ks < 2; ++ks) {
            ta[ks] = *(const bf16x8*)&Tkh[(mt * 16 + ln15) * 64 + ks * 32 + hi8];
            qa[ks] = *(const bf16x8*)&Qh [(mt * 16 + ln15) * 64 + ks * 32 + hi8];
        }
        #pragma unroll
        for (int nt = 0; nt < 4; ++nt) {
            f32x4 a = (f32x4){0.f, 0.f, 0.f, 0.f};
            #pragma unroll
            for (int ks = 0; ks < 2; ++ks) {
                a = __builtin_amdgcn_mfma_f32_16x16x32_bf16(ta[ks], ufr[nt][ks], a, 0, 0, 0);
                a = __builtin_amdgcn_mfma_f32_16x16x32_bf16(qa[ks], sfr[nt][ks], a, 0, 0, 0);
            }
            int c  = nt * 16 + ln15;
            int j0 = mt * 16 + hi4;
            ushort4 o;
            o.x = f2bf(gelu_exact(a[0]));
            o.y = f2bf(gelu_exact(a[1]));
            o.z = f2bf(gelu_exact(a[2]));
            o.w = f2bf(gelu_exact(a[3]));
            *(ushort4*)&yb[c * 68 + j0] = o;
        }
    }
    __syncthreads();

    // ---- Phase E: transposed store -> G[b][l6=c][hg][col=j][4h] ----
    unsigned short* __restrict__ Gbase = Gout + ((size_t)b << 20);  // b*64*64*256
    #pragma unroll
    for (int it = 0; it < 16; ++it) {
        int l = it * 256 + tid;
        int c = l >> 6, j = l & 63;
        ushort4 pk;
        pk.x = ((unsigned short*)(smem + 0 * 17408))[c * 68 + j];
        pk.y = ((unsigned short*)(smem + 1 * 17408))[c * 68 + j];
        pk.z = ((unsigned short*)(smem + 2 * 17408))[c * 68 + j];
        pk.w = ((unsigned short*)(smem + 3 * 17408))[c * 68 + j];
        *(ushort4*)&Gbase[((size_t)(c * 64 + hg)) * 256 + j * 4] = pk;
    }
}

// ---------------------------------------------------------------------------
// Kernel 2: out = (Wa*G + ba) * sigmoid(Wg*G + bg). One block per (b, l6):
// 32 KB G slice bulk-staged to LDS up front (deep in-flight), both M-halves
// processed sequentially (G read once). W staging software-pipelined.
// Grid 64x8 = 512 blocks (2/CU, LDS 64 KB).
// ---------------------------------------------------------------------------
__global__ __launch_bounds__(256, 2) void glu_gemm_kernel(
    const unsigned short* __restrict__ G,
    const unsigned short* __restrict__ W2,
    const float* __restrict__ bo,
    float* __restrict__ out)
{
    __shared__ __align__(16) unsigned short sG[16384];   // [hg=64][col=64][4h]
    __shared__ __align__(16) unsigned short sW[16384];   // [256 rows][64 k] swz

    const int tid  = threadIdx.x;
    const int lane = tid & 63;
    const int wv   = tid >> 6;
    const int wm   = wv >> 1;
    const int wn   = wv & 1;
    const int ln15 = lane & 15;
    const int hi   = lane >> 4;

    const int l6 = blockIdx.x;
    const int b  = blockIdx.y;
    const int l0 = l6 * 64;

    // ---- issue G slice loads (32 KB in flight) ----
    const unsigned short* gsrc = G + ((size_t)(b * 64 + l6) << 14);
    uint4 rg[8];
    #pragma unroll
    for (int i = 0; i < 8; ++i)
        rg[i] = *(const uint4*)&gsrc[i * 2048 + tid * 8];

    uint4 t[8];
    auto stageW_issue = [&](int st) {
        int pass = st >> 2, ks = st & 3, m0 = pass * 128;
        const unsigned short* src1 = W2 + (size_t)ks * 32768 + m0 * 64;
        const unsigned short* src2 = W2 + (size_t)ks * 32768 + (256 + m0) * 64;
        #pragma unroll
        for (int i = 0; i < 4; ++i) t[i]     = *(const uint4*)&src1[i * 2048 + tid * 8];
        #pragma unroll
        for (int i = 0; i < 4; ++i) t[4 + i] = *(const uint4*)&src2[i * 2048 + tid * 8];
    };
    stageW_issue(0);

    #pragma unroll
    for (int i = 0; i < 8; ++i) *(uint4*)&sG[i * 2048 + tid * 8] = rg[i];
    #pragma unroll
    for (int i = 0; i < 8; ++i) *(uint4*)&sW[i * 2048 + tid * 8] = t[i];
    __syncthreads();

    f32x4 acc[8][2];
    #pragma unroll
    for (int i = 0; i < 8; ++i)
        #pragma unroll
        for (int j = 0; j < 2; ++j) acc[i][j] = (f32x4){0.f, 0.f, 0.f, 0.f};

    for (int st = 0; st < 8; ++st) {
        const int pass = st >> 2, ks = st & 3;
        if (st < 7) stageW_issue(st + 1);        // in flight during MFMAs

        #pragma unroll
        for (int k2 = 0; k2 < 2; ++k2) {
            const int ksub = ks * 2 + k2;        // global K/32 index
            BF8 bfr[2];
            #pragma unroll
            for (int nb = 0; nb < 2; ++nb) {
                int col = wn * 32 + nb * 16 + ln15;
                int hg0 = ksub * 8 + hi * 2;
                bfr[nb].u4[0] = *(const ushort4*)&sG[(hg0 * 64 + col) * 4];
                bfr[nb].u4[1] = *(const ushort4*)&sG[((hg0 + 1) * 64 + col) * 4];
            }
            const int gl = k2 * 4 + hi;
            #pragma unroll
            for (int half = 0; half < 2; ++half) {
                #pragma unroll
                for (int mt = 0; mt < 4; ++mt) {
                    int r = half * 128 + wm * 64 + mt * 16 + ln15;
                    bf16x8 af = *(const bf16x8*)((const unsigned char*)sW + r * 128 +
                                                 ((gl ^ (r & 7)) << 4));
                    #pragma unroll
                    for (int nb = 0; nb < 2; ++nb)
                        acc[half * 4 + mt][nb] =
                            __builtin_amdgcn_mfma_f32_16x16x32_bf16(af, bfr[nb].v,
                                                                    acc[half * 4 + mt][nb], 0, 0, 0);
                }
            }
        }
        __syncthreads();

        if (ks == 3) {
            // ---- epilogue for this pass (sW region reused as fp32 tile) ----
            const int m0 = pass * 128;
            float* sEp = (float*)sW + wv * 2048;         // [64][32]
            #pragma unroll
            for (int mt = 0; mt < 4; ++mt) {
                int r0 = mt * 16 + hi * 4;
                float4 ba = *(const float4*)&bo[m0 + wm * 64 + r0];
                float4 bg = *(const float4*)&bo[256 + m0 + wm * 64 + r0];
                #pragma unroll
                for (int nb = 0; nb < 2; ++nb)
                    #pragma unroll
                    for (int rr = 0; rr < 4; ++rr) {
                        float a = acc[mt][nb][rr]     + ((const float*)&ba)[rr];
                        float g = acc[4 + mt][nb][rr] + ((const float*)&bg)[rr];
                        sEp[(r0 + rr) * 32 + nb * 16 + ln15] = a / (1.0f + __expf(-g));
                    }
            }
            __syncthreads();
            {
                const int rl = lane >> 3, c4 = (lane & 7) * 4;
                const float* sEpr = (const float*)sW + wv * 2048;
                float* obase = out + ((size_t)(b * 256 + m0 + wm * 64)) * 4096 + l0 + wn * 32;
                #pragma unroll
                for (int ps = 0; ps < 8; ++ps) {
                    int row = ps * 8 + rl;
                    float4 v = *(const float4*)&sEpr[row * 32 + c4];
                    *(float4*)&obase[(size_t)row * 4096 + c4] = v;
                }
            }
            if (st < 7) {
                #pragma unroll
                for (int i = 0; i < 8; ++i)
                    #pragma unroll
                    for (int j = 0; j < 2; ++j) acc[i][j] = (f32x4){0.f, 0.f, 0.f, 0.f};
                __syncthreads();     // sEp reads done before sW restage
            }
        }
        if (st < 7) {
            #pragma unroll
            for (int i = 0; i < 8; ++i) *(uint4*)&sW[i * 2048 + tid * 8] = t[i];
            __syncthreads();
        }
    }
}

extern "C" void kernel_launch(void* const* d_in, const int* in_sizes, int n_in,
                              void* d_out, int out_size, void* d_ws, size_t ws_size,
                              hipStream_t stream) {
    (void)in_sizes; (void)n_in; (void)out_size;
    const float* hs     = (const float*)d_in[0];
    const float* log_dt = (const float*)d_in[1];
    const float* logA   = (const float*)d_in[2];
    const float* Aim    = (const float*)d_in[3];
    const float* Cre    = (const float*)d_in[4];
    const float* Cim    = (const float*)d_in[5];
    const float* Dp     = (const float*)d_in[6];
    const float* Wout   = (const float*)d_in[7];
    const float* bout   = (const float*)d_in[8];
    float* out          = (float*)d_out;

    unsigned short* G   = (unsigned short*)d_ws;                           // 16 MB
    unsigned short* MAT = (unsigned short*)((char*)d_ws + 16777216);       // 6.29 MB
    unsigned short* W2  = (unsigned short*)((char*)d_ws + 23068672);       // 256 KB

    if (ws_size < (size_t)23330816) return;

    prep_kernel<<<dim3(384), dim3(256), 0, stream>>>(
        log_dt, logA, Aim, Cre, Cim, Dp, Wout, MAT, W2);
    s4_mfma_kernel<<<dim3(512), dim3(256), 0, stream>>>(
        hs, log_dt, logA, Aim, MAT, G);
    glu_gemm_kernel<<<dim3(64, 8), dim3(256), 0, stream>>>(
        G, W2, bout, out);
}

// Round 7
// 56.152 us; speedup vs baseline: 1.4796x; 1.4796x over previous
//
#include <hip/hip_runtime.h>
#include <hip/hip_bf16.h>

#define B_   8
#define H_   256
#define L_   4096
#define N2_  32

typedef __attribute__((ext_vector_type(8))) short bf16x8;
typedef __attribute__((ext_vector_type(4))) float f32x4;

__device__ __forceinline__ unsigned short f2bf(float x) {
    __hip_bfloat16 h = __float2bfloat16(x);
    unsigned short us;
    __builtin_memcpy(&us, &h, 2);
    return us;
}

union BF8 { ushort4 u4[2]; unsigned short s[8]; bf16x8 v; };

__device__ __forceinline__ float gelu_exact(float y) {
    return 0.5f * y * (1.0f + erff(y * 0.70710678118654752440f));
}

// hw sin/cos with explicit revolution reduction (v_sin_f32 takes revolutions)
__device__ __forceinline__ void fast_sincos(float x, float* s, float* c) {
    float rev = x * 0.15915494309189535f;
    rev = rev - floorf(rev);
    *s = __builtin_amdgcn_sinf(rev);
    *c = __builtin_amdgcn_cosf(rev);
}

// ---------------------------------------------------------------------------
// Kernel 0 (prep): blocks 0..255 = one head each (256 thr): build P, Tk
// (with D folded into taps[0]: conv(k,u)+D*u = conv(k+D*delta0, u)), Q.
// Blocks 256..383: W -> bf16 swizzled.
// ---------------------------------------------------------------------------
__global__ __launch_bounds__(256) void prep_kernel(
    const float* __restrict__ log_dt,
    const float* __restrict__ log_A_real,
    const float* __restrict__ A_imag,
    const float* __restrict__ C_re,
    const float* __restrict__ C_im,
    const float* __restrict__ Dp,
    const float* __restrict__ W,
    unsigned short* __restrict__ MAT,
    unsigned short* __restrict__ W2)
{
    const int bid = blockIdx.x;
    const int tid = threadIdx.x;
    if (bid >= 256) {
        int gq = (bid - 256) * 256 + tid;        // 0..32767
        int m = gq >> 6, t = gq & 63;
        int ks = t >> 4, sub = t & 15;
        int gr = sub >> 1, e4 = (sub & 1) * 4;
        int klog = ks * 64 + ((gr ^ (m & 7)) << 3) + e4;
        float4 wv = *(const float4*)&W[m * 256 + klog];
        ushort4 o;
        o.x = f2bf(wv.x); o.y = f2bf(wv.y); o.z = f2bf(wv.z); o.w = f2bf(wv.w);
        *(ushort4*)&W2[ks * 32768 + m * 64 + gr * 8 + e4] = o;
        return;
    }
    const int h    = bid;
    const int j    = tid & 63;
    const int part = tid >> 6;                   // 0..3 -> 8 n's each

    __shared__ float sAr[32], sAi[32], sK2r[32], sK2i[32];
    __shared__ float sTap[4][64];
    __shared__ unsigned short sQ[64 * 68];

    unsigned short* __restrict__ Pd  = MAT + (size_t)h * 12288;
    unsigned short* __restrict__ Tkd = Pd + 4096;
    unsigned short* __restrict__ Qd  = Pd + 8192;
    const float dt = __expf(log_dt[h]);

    if (tid < 32) {
        int n = tid;
        float Ar = -__expf(log_A_real[h * 32 + n]);
        float Ai = A_imag[h * 32 + n];
        float er = __expf(dt * Ar);
        float s, c; fast_sincos(dt * Ai, &s, &c);
        float wr = er * c, wi = er * s;
        float Cr = C_re[h * 32 + n], Ci = C_im[h * 32 + n];
        float den = Ar * Ar + Ai * Ai;
        float nr = wr - 1.0f, ni = wi;
        float qr = (nr * Ar + ni * Ai) / den;
        float qi = (ni * Ar - nr * Ai) / den;
        sAr[n] = Ar; sAi[n] = Ai;
        sK2r[n] = 2.0f * (Cr * qr - Ci * qi);
        sK2i[n] = 2.0f * (Cr * qi + Ci * qr);
    }
    __syncthreads();

    // ---- P[2n][j] = Re(w_n^{63-j}), P[2n+1][j] = Im ----
    {
        float pdt = dt * (float)(63 - j);
        #pragma unroll
        for (int q = 0; q < 8; ++q) {
            int n = part * 8 + q;
            float mag = __expf(pdt * sAr[n]);
            float s, c; fast_sincos(pdt * sAi[n], &s, &c);
            Pd[(2 * n)     * 64 + j] = f2bf(mag * c);
            Pd[(2 * n + 1) * 64 + j] = f2bf(mag * s);
        }
    }
    // ---- taps partial sums + Q staging ----
    {
        float jdt = dt * (float)j;
        float acc = 0.0f;
        #pragma unroll
        for (int q = 0; q < 8; ++q) {
            int n = part * 8 + q;
            float mag = __expf(jdt * sAr[n]);
            float s, c; fast_sincos(jdt * sAi[n], &s, &c);
            acc = fmaf(sK2r[n], mag * c, fmaf(-sK2i[n], mag * s, acc));
        }
        sTap[part][j] = acc;
        float j1dt = dt * (float)(j + 1);
        #pragma unroll
        for (int q = 0; q < 8; ++q) {
            int n = part * 8 + q;
            float mag = __expf(j1dt * sAr[n]);
            float s, c; fast_sincos(j1dt * sAi[n], &s, &c);
            float wpr = mag * c, wpi = mag * s;
            sQ[j * 68 + 2 * n]     = f2bf(sK2r[n] * wpr - sK2i[n] * wpi);
            sQ[j * 68 + 2 * n + 1] = f2bf(-(sK2r[n] * wpi + sK2i[n] * wpr));
        }
    }
    __syncthreads();
    if (part == 0) {
        float v = sTap[0][j] + sTap[1][j] + sTap[2][j] + sTap[3][j];
        if (j == 0) v += Dp[h];                  // fold D-skip into tap 0
        sTap[0][j] = v;
    }
    __syncthreads();

    // ---- Tk[r][c] = taps[r-c] (r>=c) ----
    {
        int r  = tid >> 2;
        int c0 = (tid & 3) * 16;
        #pragma unroll
        for (int cc = 0; cc < 16; cc += 4) {
            int c = c0 + cc;
            ushort4 v;
            v.x = (r - c     >= 0) ? f2bf(sTap[0][r - c])     : (unsigned short)0;
            v.y = (r - c - 1 >= 0) ? f2bf(sTap[0][r - c - 1]) : (unsigned short)0;
            v.z = (r - c - 2 >= 0) ? f2bf(sTap[0][r - c - 2]) : (unsigned short)0;
            v.w = (r - c - 3 >= 0) ? f2bf(sTap[0][r - c - 3]) : (unsigned short)0;
            *(ushort4*)&Tkd[r * 64 + c] = v;
        }
    }
    // ---- Q cooperative coalesced store ----
    #pragma unroll
    for (int it = 0; it < 4; ++it) {
        int quad = it * 256 + tid;
        int row = quad >> 4, c4 = (quad & 15) * 4;
        ushort4 v;
        v.x = sQ[row * 68 + c4];     v.y = sQ[row * 68 + c4 + 1];
        v.z = sQ[row * 68 + c4 + 2]; v.w = sQ[row * 68 + c4 + 3];
        *(ushort4*)&Qd[row * 64 + c4] = v;
    }
}

// ---------------------------------------------------------------------------
// Kernel 1: MFMA-based chunked scan. D folded into Tk -> no u re-read.
// Output G stored bf16 [b][hg][l][4h] for the GEMM's direct B-frag loads.
// ---------------------------------------------------------------------------
__global__ __launch_bounds__(256, 2) void s4_mfma_kernel(
    const float* __restrict__ u,
    const float* __restrict__ log_dt,
    const float* __restrict__ log_A_real,
    const float* __restrict__ A_imag,
    const unsigned short* __restrict__ MAT,
    unsigned short* __restrict__ Gout)
{
    __shared__ __align__(16) unsigned char smem[4 * 17408];   // 68 KB
    const int tid  = threadIdx.x;
    const int w    = tid >> 6;
    const int lane = tid & 63;
    const int ln15 = lane & 15;
    const int hi4  = (lane >> 4) * 4;
    const int hi8  = (lane >> 4) * 8;
    const int bid  = blockIdx.x;
    const int b    = bid >> 6, hg = bid & 63;
    const int h    = hg * 4 + w;

    float* Eb = (float*)(smem + w * 17408);                    // [c][68] fp32
    unsigned short* yb = (unsigned short*)(smem + w * 17408);  // bf16 overlay

    const float* __restrict__ urow = u + ((size_t)(b * H_ + h)) * L_;
    const unsigned short* __restrict__ Ph  = MAT + (size_t)h * 12288;
    const unsigned short* __restrict__ Tkh = Ph + 4096;
    const unsigned short* __restrict__ Qh  = Ph + 8192;

    // w^64 for the serial scan
    float wTr, wTi;
    {
        int n = lane & 31;
        float dt = expf(log_dt[h]);
        float Ar = -expf(log_A_real[h * 32 + n]);
        float Ai = A_imag[h * 32 + n];
        float er = expf(dt * Ar); float s, c; sincosf(dt * Ai, &s, &c);
        float pr = er * c, pi = er * s;
        #pragma unroll
        for (int k = 0; k < 6; ++k) { float a2 = pr*pr - pi*pi, b2 = 2.0f*pr*pi; pr = a2; pi = b2; }
        wTr = pr; wTi = pi;
    }

    // ---- Phase A: U fragments (kept for phase C) + E = P*U ----
    bf16x8 ufr[4][2];
    #pragma unroll
    for (int nt = 0; nt < 4; ++nt) {
        int c = nt * 16 + ln15;
        #pragma unroll
        for (int ks = 0; ks < 2; ++ks) {
            const float* p = urow + c * 64 + ks * 32 + hi8;
            float4 lo = *(const float4*)p;
            float4 hi = *(const float4*)(p + 4);
            BF8 t8;
            t8.s[0]=f2bf(lo.x); t8.s[1]=f2bf(lo.y); t8.s[2]=f2bf(lo.z); t8.s[3]=f2bf(lo.w);
            t8.s[4]=f2bf(hi.x); t8.s[5]=f2bf(hi.y); t8.s[6]=f2bf(hi.z); t8.s[7]=f2bf(hi.w);
            ufr[nt][ks] = t8.v;
        }
    }
    #pragma unroll
    for (int mt = 0; mt < 4; ++mt) {
        bf16x8 pa[2];
        #pragma unroll
        for (int ks = 0; ks < 2; ++ks)
            pa[ks] = *(const bf16x8*)&Ph[(mt * 16 + ln15) * 64 + ks * 32 + hi8];
        f32x4 e[4];
        #pragma unroll
        for (int nt = 0; nt < 4; ++nt) e[nt] = (f32x4){0.f, 0.f, 0.f, 0.f};
        #pragma unroll
        for (int ks = 0; ks < 2; ++ks)
            #pragma unroll
            for (int nt = 0; nt < 4; ++nt)
                e[nt] = __builtin_amdgcn_mfma_f32_16x16x32_bf16(pa[ks], ufr[nt][ks], e[nt], 0, 0, 0);
        #pragma unroll
        for (int nt = 0; nt < 4; ++nt)
            *(f32x4*)&Eb[(nt * 16 + ln15) * 68 + mt * 16 + hi4] = e[nt];
    }
    __syncthreads();

    // ---- Phase B: serial scan over 64 chunks; leaves INCOMING state S[c] ----
    if (lane < 32) {
        int n2 = 2 * lane;
        float Xr = 0.0f, Xi = 0.0f;
        float2 e = *(float2*)&Eb[n2];
        #pragma unroll 4
        for (int c = 0; c < 64; ++c) {
            float2 en = e;
            if (c < 63) en = *(float2*)&Eb[(c + 1) * 68 + n2];
            *(float2*)&Eb[c * 68 + n2] = make_float2(Xr, Xi);
            float nXr = fmaf(wTr, Xr, fmaf(-wTi, Xi, e.x));
            float nXi = fmaf(wTi, Xr, fmaf( wTr, Xi, e.y));
            Xr = nXr; Xi = nXi; e = en;
        }
    }
    __syncthreads();

    // ---- Phase C: Y = Tk*U + Q*S (D folded in Tk), GELU, bf16 ----
    bf16x8 sfr[4][2];
    #pragma unroll
    for (int nt = 0; nt < 4; ++nt) {
        int c = nt * 16 + ln15;
        #pragma unroll
        for (int ks = 0; ks < 2; ++ks) {
            float4 lo = *(const float4*)&Eb[c * 68 + ks * 32 + hi8];
            float4 hi = *(const float4*)&Eb[c * 68 + ks * 32 + hi8 + 4];
            BF8 t8;
            t8.s[0]=f2bf(lo.x); t8.s[1]=f2bf(lo.y); t8.s[2]=f2bf(lo.z); t8.s[3]=f2bf(lo.w);
            t8.s[4]=f2bf(hi.x); t8.s[5]=f2bf(hi.y); t8.s[6]=f2bf(hi.z); t8.s[7]=f2bf(hi.w);
            sfr[nt][ks] = t8.v;
        }
    }
    #pragma unroll
    for (int mt = 0; mt < 4; ++mt) {
        bf16x8 ta[2], qa[2];
        #pragma unroll
        for (int ks = 0; ks < 2; ++ks) {
            ta[ks] = *(const bf16x8*)&Tkh[(mt * 16 + ln15) * 64 + ks * 32 + hi8];
            qa[ks] = *(const bf16x8*)&Qh [(mt * 16 + ln15) * 64 + ks * 32 + hi8];
        }
        #pragma unroll
        for (int nt = 0; nt < 4; ++nt) {
            f32x4 a = (f32x4){0.f, 0.f, 0.f, 0.f};
            #pragma unroll
            for (int ks = 0; ks < 2; ++ks) {
                a = __builtin_amdgcn_mfma_f32_16x16x32_bf16(ta[ks], ufr[nt][ks], a, 0, 0, 0);
                a = __builtin_amdgcn_mfma_f32_16x16x32_bf16(qa[ks], sfr[nt][ks], a, 0, 0, 0);
            }
            int c  = nt * 16 + ln15;
            int j0 = mt * 16 + hi4;
            ushort4 o;
            o.x = f2bf(gelu_exact(a[0]));
            o.y = f2bf(gelu_exact(a[1]));
            o.z = f2bf(gelu_exact(a[2]));
            o.w = f2bf(gelu_exact(a[3]));
            *(ushort4*)&yb[c * 68 + j0] = o;
        }
    }
    __syncthreads();

    // ---- Phase E: coalesced transposed store -> G[b][hg][l][4h] ----
    unsigned short* __restrict__ Grow = Gout + ((size_t)(b * 64 + hg)) * (L_ * 4);
    #pragma unroll
    for (int it = 0; it < 16; ++it) {
        int l = it * 256 + tid;
        int c = l >> 6, j = l & 63;
        ushort4 pk;
        pk.x = ((unsigned short*)(smem + 0 * 17408))[c * 68 + j];
        pk.y = ((unsigned short*)(smem + 1 * 17408))[c * 68 + j];
        pk.z = ((unsigned short*)(smem + 2 * 17408))[c * 68 + j];
        pk.w = ((unsigned short*)(smem + 3 * 17408))[c * 68 + j];
        *(ushort4*)&Grow[(size_t)l * 4] = pk;
    }
}

// ---------------------------------------------------------------------------
// Kernel 2 (round-4/5 proven structure): out = (Wa*G+ba) * sigmoid(Wg*G+bg).
// Grid 64x2x8 = 1024 blocks of 256 thr, 4 blocks/CU. Block tile: 128 GLU
// pairs x 64 l. W staged in 32KB XOR-swizzled LDS per 64-k slice; B (G)
// register double-buffered direct from global. Full-line float4 stores.
// ---------------------------------------------------------------------------
__global__ __launch_bounds__(256, 4) void glu_gemm_kernel(
    const unsigned short* __restrict__ G,
    const unsigned short* __restrict__ W2,
    const float* __restrict__ bo,
    float* __restrict__ out)
{
    __shared__ __align__(16) unsigned char smem[36864];  // 36 KB
    unsigned short* sW = (unsigned short*)smem;          // [256 rows][64 k] swz

    const int tid  = threadIdx.x;
    const int lane = tid & 63;
    const int wv   = tid >> 6;         // 0..3
    const int wm   = wv >> 1;          // 0..1 (m-half within block)
    const int wn   = wv & 1;           // 0..1 (n-half)
    const int ln15 = lane & 15;
    const int hi   = lane >> 4;        // 0..3

    const int l0 = blockIdx.x * 64;
    const int m0 = blockIdx.y * 128;   // 0 or 128 (GLU-pair offset)
    const int b  = blockIdx.z;
    const int col0 = l0 + wn * 32 + ln15;

    f32x4 acc[8][2];
    #pragma unroll
    for (int i = 0; i < 8; ++i)
        #pragma unroll
        for (int j = 0; j < 2; ++j) acc[i][j] = (f32x4){0.f, 0.f, 0.f, 0.f};

    BF8 bb[2][2];
    auto loadB = [&](int ksub, BF8* dst) {
        int hg0 = ksub * 8 + hi * 2;
        size_t base = ((size_t)(b * 64 + hg0) * 4096 + col0) * 4;
        dst[0].u4[0] = *(const ushort4*)&G[base];
        dst[0].u4[1] = *(const ushort4*)&G[base + 16384];
        dst[1].u4[0] = *(const ushort4*)&G[base + 64];
        dst[1].u4[1] = *(const ushort4*)&G[base + 16384 + 64];
    };
    loadB(0, bb[0]);

    for (int ksub = 0; ksub < 8; ++ksub) {
        if ((ksub & 1) == 0) {
            const int ks = ksub >> 1;
            __syncthreads();
            const unsigned short* src1 = W2 + (size_t)ks * 32768 + m0 * 64;
            const unsigned short* src2 = W2 + (size_t)ks * 32768 + (256 + m0) * 64;
            uint4 t[8];
            #pragma unroll
            for (int i = 0; i < 4; ++i) t[i]     = *(const uint4*)&src1[i * 2048 + tid * 8];
            #pragma unroll
            for (int i = 0; i < 4; ++i) t[4 + i] = *(const uint4*)&src2[i * 2048 + tid * 8];
            #pragma unroll
            for (int i = 0; i < 8; ++i)
                *(uint4*)&sW[i * 2048 + tid * 8] = t[i];
            __syncthreads();
        }
        if (ksub < 7) loadB(ksub + 1, bb[(ksub + 1) & 1]);
        const BF8* bc = bb[ksub & 1];
        const int gl = (ksub & 1) * 4 + hi;
        #pragma unroll
        for (int half = 0; half < 2; ++half) {
            bf16x8 af[4];
            #pragma unroll
            for (int mt = 0; mt < 4; ++mt) {
                int r = half * 128 + wm * 64 + mt * 16 + ln15;
                af[mt] = *(const bf16x8*)((const unsigned char*)sW + r * 128 + ((gl ^ (r & 7)) << 4));
            }
            #pragma unroll
            for (int mt = 0; mt < 4; ++mt)
                #pragma unroll
                for (int nb = 0; nb < 2; ++nb)
                    acc[half * 4 + mt][nb] =
                        __builtin_amdgcn_mfma_f32_16x16x32_bf16(af[mt], bc[nb].v,
                                                                acc[half * 4 + mt][nb], 0, 0, 0);
        }
    }

    // ---- epilogue: in-register GLU -> per-wave LDS [64][36] -> coalesced out
    __syncthreads();
    float* sEp = (float*)smem + wv * 2304;   // 64*36 floats per wave
    #pragma unroll
    for (int mt = 0; mt < 4; ++mt) {
        int r0 = mt * 16 + hi * 4;
        float4 ba = *(const float4*)&bo[m0 + wm * 64 + r0];
        float4 bg = *(const float4*)&bo[256 + m0 + wm * 64 + r0];
        #pragma unroll
        for (int nb = 0; nb < 2; ++nb) {
            #pragma unroll
            for (int rr = 0; rr < 4; ++rr) {
                float a = acc[mt][nb][rr]     + ((const float*)&ba)[rr];
                float g = acc[4 + mt][nb][rr] + ((const float*)&bg)[rr];
                sEp[(r0 + rr) * 36 + nb * 16 + ln15] = a / (1.0f + expf(-g));
            }
        }
    }
    __syncthreads();
    {
        const int rl = lane >> 3;
        const int c4 = (lane & 7) * 4;
        float* obase = out + ((size_t)(b * 256 + m0 + wm * 64)) * 4096 + l0 + wn * 32;
        #pragma unroll
        for (int ps = 0; ps < 8; ++ps) {
            int row = ps * 8 + rl;
            float4 v = *(const float4*)&sEp[row * 36 + c4];
            *(float4*)&obase[(size_t)row * 4096 + c4] = v;
        }
    }
}

extern "C" void kernel_launch(void* const* d_in, const int* in_sizes, int n_in,
                              void* d_out, int out_size, void* d_ws, size_t ws_size,
                              hipStream_t stream) {
    (void)in_sizes; (void)n_in; (void)out_size;
    const float* hs     = (const float*)d_in[0];
    const float* log_dt = (const float*)d_in[1];
    const float* logA   = (const float*)d_in[2];
    const float* Aim    = (const float*)d_in[3];
    const float* Cre    = (const float*)d_in[4];
    const float* Cim    = (const float*)d_in[5];
    const float* Dp     = (const float*)d_in[6];
    const float* Wout   = (const float*)d_in[7];
    const float* bout   = (const float*)d_in[8];
    float* out          = (float*)d_out;

    unsigned short* G   = (unsigned short*)d_ws;                           // 16 MB
    unsigned short* MAT = (unsigned short*)((char*)d_ws + 16777216);       // 6.29 MB
    unsigned short* W2  = (unsigned short*)((char*)d_ws + 23068672);       // 256 KB

    if (ws_size < (size_t)23330816) return;

    prep_kernel<<<dim3(384), dim3(256), 0, stream>>>(
        log_dt, logA, Aim, Cre, Cim, Dp, Wout, MAT, W2);
    s4_mfma_kernel<<<dim3(512), dim3(256), 0, stream>>>(
        hs, log_dt, logA, Aim, MAT, G);
    glu_gemm_kernel<<<dim3(64, 2, 8), dim3(256), 0, stream>>>(
        G, W2, bout, out);
}

// Round 8
// 54.884 us; speedup vs baseline: 1.5138x; 1.0231x over previous
//
#include <hip/hip_runtime.h>
#include <hip/hip_bf16.h>

#define B_   8
#define H_   256
#define L_   4096
#define N2_  32

typedef __attribute__((ext_vector_type(8))) short bf16x8;
typedef __attribute__((ext_vector_type(4))) float f32x4;

__device__ __forceinline__ unsigned short f2bf(float x) {
    __hip_bfloat16 h = __float2bfloat16(x);
    unsigned short us;
    __builtin_memcpy(&us, &h, 2);
    return us;
}

union BF8 { ushort4 u4[2]; unsigned short s[8]; bf16x8 v; };

__device__ __forceinline__ float gelu_exact(float y) {
    return 0.5f * y * (1.0f + erff(y * 0.70710678118654752440f));
}

// hw sin/cos with explicit revolution reduction (v_sin_f32 takes revolutions)
__device__ __forceinline__ void fast_sincos(float x, float* s, float* c) {
    float rev = x * 0.15915494309189535f;
    rev = rev - floorf(rev);
    *s = __builtin_amdgcn_sinf(rev);
    *c = __builtin_amdgcn_cosf(rev);
}

// ---------------------------------------------------------------------------
// Kernel 0 (prep): blocks 0..255 = one head each (256 thr): build P, Tk
// (with D folded into taps[0]: conv(k,u)+D*u = conv(k+D*delta0, u)), Q.
// Blocks 256..383: W -> bf16 swizzled.
// ---------------------------------------------------------------------------
__global__ __launch_bounds__(256) void prep_kernel(
    const float* __restrict__ log_dt,
    const float* __restrict__ log_A_real,
    const float* __restrict__ A_imag,
    const float* __restrict__ C_re,
    const float* __restrict__ C_im,
    const float* __restrict__ Dp,
    const float* __restrict__ W,
    unsigned short* __restrict__ MAT,
    unsigned short* __restrict__ W2)
{
    const int bid = blockIdx.x;
    const int tid = threadIdx.x;
    if (bid >= 256) {
        int gq = (bid - 256) * 256 + tid;        // 0..32767
        int m = gq >> 6, t = gq & 63;
        int ks = t >> 4, sub = t & 15;
        int gr = sub >> 1, e4 = (sub & 1) * 4;
        int klog = ks * 64 + ((gr ^ (m & 7)) << 3) + e4;
        float4 wv = *(const float4*)&W[m * 256 + klog];
        ushort4 o;
        o.x = f2bf(wv.x); o.y = f2bf(wv.y); o.z = f2bf(wv.z); o.w = f2bf(wv.w);
        *(ushort4*)&W2[ks * 32768 + m * 64 + gr * 8 + e4] = o;
        return;
    }
    const int h    = bid;
    const int j    = tid & 63;
    const int part = tid >> 6;                   // 0..3 -> 8 n's each

    __shared__ float sAr[32], sAi[32], sK2r[32], sK2i[32];
    __shared__ float sTap[4][64];
    __shared__ unsigned short sQ[64 * 68];

    unsigned short* __restrict__ Pd  = MAT + (size_t)h * 12288;
    unsigned short* __restrict__ Tkd = Pd + 4096;
    unsigned short* __restrict__ Qd  = Pd + 8192;
    const float dt = __expf(log_dt[h]);

    if (tid < 32) {
        int n = tid;
        float Ar = -__expf(log_A_real[h * 32 + n]);
        float Ai = A_imag[h * 32 + n];
        float er = __expf(dt * Ar);
        float s, c; fast_sincos(dt * Ai, &s, &c);
        float wr = er * c, wi = er * s;
        float Cr = C_re[h * 32 + n], Ci = C_im[h * 32 + n];
        float den = Ar * Ar + Ai * Ai;
        float nr = wr - 1.0f, ni = wi;
        float qr = (nr * Ar + ni * Ai) / den;
        float qi = (ni * Ar - nr * Ai) / den;
        sAr[n] = Ar; sAi[n] = Ai;
        sK2r[n] = 2.0f * (Cr * qr - Ci * qi);
        sK2i[n] = 2.0f * (Cr * qi + Ci * qr);
    }
    __syncthreads();

    // ---- P[2n][j] = Re(w_n^{63-j}), P[2n+1][j] = Im ----
    {
        float pdt = dt * (float)(63 - j);
        #pragma unroll
        for (int q = 0; q < 8; ++q) {
            int n = part * 8 + q;
            float mag = __expf(pdt * sAr[n]);
            float s, c; fast_sincos(pdt * sAi[n], &s, &c);
            Pd[(2 * n)     * 64 + j] = f2bf(mag * c);
            Pd[(2 * n + 1) * 64 + j] = f2bf(mag * s);
        }
    }
    // ---- taps partial sums + Q staging ----
    {
        float jdt = dt * (float)j;
        float acc = 0.0f;
        #pragma unroll
        for (int q = 0; q < 8; ++q) {
            int n = part * 8 + q;
            float mag = __expf(jdt * sAr[n]);
            float s, c; fast_sincos(jdt * sAi[n], &s, &c);
            acc = fmaf(sK2r[n], mag * c, fmaf(-sK2i[n], mag * s, acc));
        }
        sTap[part][j] = acc;
        float j1dt = dt * (float)(j + 1);
        #pragma unroll
        for (int q = 0; q < 8; ++q) {
            int n = part * 8 + q;
            float mag = __expf(j1dt * sAr[n]);
            float s, c; fast_sincos(j1dt * sAi[n], &s, &c);
            float wpr = mag * c, wpi = mag * s;
            sQ[j * 68 + 2 * n]     = f2bf(sK2r[n] * wpr - sK2i[n] * wpi);
            sQ[j * 68 + 2 * n + 1] = f2bf(-(sK2r[n] * wpi + sK2i[n] * wpr));
        }
    }
    __syncthreads();
    if (part == 0) {
        float v = sTap[0][j] + sTap[1][j] + sTap[2][j] + sTap[3][j];
        if (j == 0) v += Dp[h];                  // fold D-skip into tap 0
        sTap[0][j] = v;
    }
    __syncthreads();

    // ---- Tk[r][c] = taps[r-c] (r>=c) ----
    {
        int r  = tid >> 2;
        int c0 = (tid & 3) * 16;
        #pragma unroll
        for (int cc = 0; cc < 16; cc += 4) {
            int c = c0 + cc;
            ushort4 v;
            v.x = (r - c     >= 0) ? f2bf(sTap[0][r - c])     : (unsigned short)0;
            v.y = (r - c - 1 >= 0) ? f2bf(sTap[0][r - c - 1]) : (unsigned short)0;
            v.z = (r - c - 2 >= 0) ? f2bf(sTap[0][r - c - 2]) : (unsigned short)0;
            v.w = (r - c - 3 >= 0) ? f2bf(sTap[0][r - c - 3]) : (unsigned short)0;
            *(ushort4*)&Tkd[r * 64 + c] = v;
        }
    }
    // ---- Q cooperative coalesced store ----
    #pragma unroll
    for (int it = 0; it < 4; ++it) {
        int quad = it * 256 + tid;
        int row = quad >> 4, c4 = (quad & 15) * 4;
        ushort4 v;
        v.x = sQ[row * 68 + c4];     v.y = sQ[row * 68 + c4 + 1];
        v.z = sQ[row * 68 + c4 + 2]; v.w = sQ[row * 68 + c4 + 3];
        *(ushort4*)&Qd[row * 64 + c4] = v;
    }
}

// ---------------------------------------------------------------------------
// Kernel 1: MFMA-based chunked scan. D folded into Tk -> no u re-read.
// Output G stored bf16 [b][hg][l][4h] for the GEMM's direct B-frag loads.
// ---------------------------------------------------------------------------
__global__ __launch_bounds__(256, 2) void s4_mfma_kernel(
    const float* __restrict__ u,
    const float* __restrict__ log_dt,
    const float* __restrict__ log_A_real,
    const float* __restrict__ A_imag,
    const unsigned short* __restrict__ MAT,
    unsigned short* __restrict__ Gout)
{
    __shared__ __align__(16) unsigned char smem[4 * 17408];   // 68 KB
    const int tid  = threadIdx.x;
    const int w    = tid >> 6;
    const int lane = tid & 63;
    const int ln15 = lane & 15;
    const int hi4  = (lane >> 4) * 4;
    const int hi8  = (lane >> 4) * 8;
    const int bid  = blockIdx.x;
    const int b    = bid >> 6, hg = bid & 63;
    const int h    = hg * 4 + w;

    float* Eb = (float*)(smem + w * 17408);                    // [c][68] fp32
    unsigned short* yb = (unsigned short*)(smem + w * 17408);  // bf16 overlay

    const float* __restrict__ urow = u + ((size_t)(b * H_ + h)) * L_;
    const unsigned short* __restrict__ Ph  = MAT + (size_t)h * 12288;
    const unsigned short* __restrict__ Tkh = Ph + 4096;
    const unsigned short* __restrict__ Qh  = Ph + 8192;

    // w^64 for the serial scan
    float wTr, wTi;
    {
        int n = lane & 31;
        float dt = expf(log_dt[h]);
        float Ar = -expf(log_A_real[h * 32 + n]);
        float Ai = A_imag[h * 32 + n];
        float er = expf(dt * Ar); float s, c; sincosf(dt * Ai, &s, &c);
        float pr = er * c, pi = er * s;
        #pragma unroll
        for (int k = 0; k < 6; ++k) { float a2 = pr*pr - pi*pi, b2 = 2.0f*pr*pi; pr = a2; pi = b2; }
        wTr = pr; wTi = pi;
    }

    // ---- Phase A: U fragments (kept for phase C) + E = P*U ----
    bf16x8 ufr[4][2];
    #pragma unroll
    for (int nt = 0; nt < 4; ++nt) {
        int c = nt * 16 + ln15;
        #pragma unroll
        for (int ks = 0; ks < 2; ++ks) {
            const float* p = urow + c * 64 + ks * 32 + hi8;
            float4 lo = *(const float4*)p;
            float4 hi = *(const float4*)(p + 4);
            BF8 t8;
            t8.s[0]=f2bf(lo.x); t8.s[1]=f2bf(lo.y); t8.s[2]=f2bf(lo.z); t8.s[3]=f2bf(lo.w);
            t8.s[4]=f2bf(hi.x); t8.s[5]=f2bf(hi.y); t8.s[6]=f2bf(hi.z); t8.s[7]=f2bf(hi.w);
            ufr[nt][ks] = t8.v;
        }
    }
    #pragma unroll
    for (int mt = 0; mt < 4; ++mt) {
        bf16x8 pa[2];
        #pragma unroll
        for (int ks = 0; ks < 2; ++ks)
            pa[ks] = *(const bf16x8*)&Ph[(mt * 16 + ln15) * 64 + ks * 32 + hi8];
        f32x4 e[4];
        #pragma unroll
        for (int nt = 0; nt < 4; ++nt) e[nt] = (f32x4){0.f, 0.f, 0.f, 0.f};
        #pragma unroll
        for (int ks = 0; ks < 2; ++ks)
            #pragma unroll
            for (int nt = 0; nt < 4; ++nt)
                e[nt] = __builtin_amdgcn_mfma_f32_16x16x32_bf16(pa[ks], ufr[nt][ks], e[nt], 0, 0, 0);
        #pragma unroll
        for (int nt = 0; nt < 4; ++nt)
            *(f32x4*)&Eb[(nt * 16 + ln15) * 68 + mt * 16 + hi4] = e[nt];
    }
    __syncthreads();

    // ---- Phase B: serial scan over 64 chunks; leaves INCOMING state S[c] ----
    if (lane < 32) {
        int n2 = 2 * lane;
        float Xr = 0.0f, Xi = 0.0f;
        float2 e = *(float2*)&Eb[n2];
        #pragma unroll 4
        for (int c = 0; c < 64; ++c) {
            float2 en = e;
            if (c < 63) en = *(float2*)&Eb[(c + 1) * 68 + n2];
            *(float2*)&Eb[c * 68 + n2] = make_float2(Xr, Xi);
            float nXr = fmaf(wTr, Xr, fmaf(-wTi, Xi, e.x));
            float nXi = fmaf(wTi, Xr, fmaf( wTr, Xi, e.y));
            Xr = nXr; Xi = nXi; e = en;
        }
    }
    __syncthreads();

    // ---- Phase C: Y = Tk*U + Q*S (D folded in Tk), GELU, bf16 ----
    bf16x8 sfr[4][2];
    #pragma unroll
    for (int nt = 0; nt < 4; ++nt) {
        int c = nt * 16 + ln15;
        #pragma unroll
        for (int ks = 0; ks < 2; ++ks) {
            float4 lo = *(const float4*)&Eb[c * 68 + ks * 32 + hi8];
            float4 hi = *(const float4*)&Eb[c * 68 + ks * 32 + hi8 + 4];
            BF8 t8;
            t8.s[0]=f2bf(lo.x); t8.s[1]=f2bf(lo.y); t8.s[2]=f2bf(lo.z); t8.s[3]=f2bf(lo.w);
            t8.s[4]=f2bf(hi.x); t8.s[5]=f2bf(hi.y); t8.s[6]=f2bf(hi.z); t8.s[7]=f2bf(hi.w);
            sfr[nt][ks] = t8.v;
        }
    }
    #pragma unroll
    for (int mt = 0; mt < 4; ++mt) {
        bf16x8 ta[2], qa[2];
        #pragma unroll
        for (int ks = 0; ks < 2; ++ks) {
            ta[ks] = *(const bf16x8*)&Tkh[(mt * 16 + ln15) * 64 + ks * 32 + hi8];
            qa[ks] = *(const bf16x8*)&Qh [(mt * 16 + ln15) * 64 + ks * 32 + hi8];
        }
        #pragma unroll
        for (int nt = 0; nt < 4; ++nt) {
            f32x4 a = (f32x4){0.f, 0.f, 0.f, 0.f};
            #pragma unroll
            for (int ks = 0; ks < 2; ++ks) {
                a = __builtin_amdgcn_mfma_f32_16x16x32_bf16(ta[ks], ufr[nt][ks], a, 0, 0, 0);
                a = __builtin_amdgcn_mfma_f32_16x16x32_bf16(qa[ks], sfr[nt][ks], a, 0, 0, 0);
            }
            int c  = nt * 16 + ln15;
            int j0 = mt * 16 + hi4;
            ushort4 o;
            o.x = f2bf(gelu_exact(a[0]));
            o.y = f2bf(gelu_exact(a[1]));
            o.z = f2bf(gelu_exact(a[2]));
            o.w = f2bf(gelu_exact(a[3]));
            *(ushort4*)&yb[c * 68 + j0] = o;
        }
    }
    __syncthreads();

    // ---- Phase E: coalesced transposed store -> G[b][hg][l][4h] ----
    unsigned short* __restrict__ Grow = Gout + ((size_t)(b * 64 + hg)) * (L_ * 4);
    #pragma unroll
    for (int it = 0; it < 16; ++it) {
        int l = it * 256 + tid;
        int c = l >> 6, j = l & 63;
        ushort4 pk;
        pk.x = ((unsigned short*)(smem + 0 * 17408))[c * 68 + j];
        pk.y = ((unsigned short*)(smem + 1 * 17408))[c * 68 + j];
        pk.z = ((unsigned short*)(smem + 2 * 17408))[c * 68 + j];
        pk.w = ((unsigned short*)(smem + 3 * 17408))[c * 68 + j];
        *(ushort4*)&Grow[(size_t)l * 4] = pk;
    }
}

// ---------------------------------------------------------------------------
// Kernel 2: out = (Wa*G+ba) * sigmoid(Wg*G+bg). Round-4 structure + 4-deep
// register prefetch ring on B (G) loads to cover L3/HBM latency.
// Grid 64x2x8 = 1024 blocks of 256 thr. W staged in 32KB XOR-swizzled LDS.
// ---------------------------------------------------------------------------
__global__ __launch_bounds__(256, 3) void glu_gemm_kernel(
    const unsigned short* __restrict__ G,
    const unsigned short* __restrict__ W2,
    const float* __restrict__ bo,
    float* __restrict__ out)
{
    __shared__ __align__(16) unsigned char smem[36864];  // 36 KB
    unsigned short* sW = (unsigned short*)smem;          // [256 rows][64 k] swz

    const int tid  = threadIdx.x;
    const int lane = tid & 63;
    const int wv   = tid >> 6;         // 0..3
    const int wm   = wv >> 1;          // 0..1 (m-half within block)
    const int wn   = wv & 1;           // 0..1 (n-half)
    const int ln15 = lane & 15;
    const int hi   = lane >> 4;        // 0..3

    const int l0 = blockIdx.x * 64;
    const int m0 = blockIdx.y * 128;   // 0 or 128 (GLU-pair offset)
    const int b  = blockIdx.z;
    const int col0 = l0 + wn * 32 + ln15;

    f32x4 acc[8][2];
    #pragma unroll
    for (int i = 0; i < 8; ++i)
        #pragma unroll
        for (int j = 0; j < 2; ++j) acc[i][j] = (f32x4){0.f, 0.f, 0.f, 0.f};

    BF8 bb[4][2];                      // 4-deep prefetch ring
    auto loadB = [&](int ksub, BF8* dst) {
        int hg0 = ksub * 8 + hi * 2;
        size_t base = ((size_t)(b * 64 + hg0) * 4096 + col0) * 4;
        dst[0].u4[0] = *(const ushort4*)&G[base];
        dst[0].u4[1] = *(const ushort4*)&G[base + 16384];
        dst[1].u4[0] = *(const ushort4*)&G[base + 64];
        dst[1].u4[1] = *(const ushort4*)&G[base + 16384 + 64];
    };
    #pragma unroll
    for (int p = 0; p < 4; ++p) loadB(p, bb[p]);

    #pragma unroll
    for (int ksub = 0; ksub < 8; ++ksub) {
        if ((ksub & 1) == 0) {
            const int ks = ksub >> 1;
            __syncthreads();
            const unsigned short* src1 = W2 + (size_t)ks * 32768 + m0 * 64;
            const unsigned short* src2 = W2 + (size_t)ks * 32768 + (256 + m0) * 64;
            uint4 t[8];
            #pragma unroll
            for (int i = 0; i < 4; ++i) t[i]     = *(const uint4*)&src1[i * 2048 + tid * 8];
            #pragma unroll
            for (int i = 0; i < 4; ++i) t[4 + i] = *(const uint4*)&src2[i * 2048 + tid * 8];
            #pragma unroll
            for (int i = 0; i < 8; ++i)
                *(uint4*)&sW[i * 2048 + tid * 8] = t[i];
            __syncthreads();
        }
        const int slot = ksub & 3;
        const int gl = (ksub & 1) * 4 + hi;
        #pragma unroll
        for (int half = 0; half < 2; ++half) {
            bf16x8 af[4];
            #pragma unroll
            for (int mt = 0; mt < 4; ++mt) {
                int r = half * 128 + wm * 64 + mt * 16 + ln15;
                af[mt] = *(const bf16x8*)((const unsigned char*)sW + r * 128 + ((gl ^ (r & 7)) << 4));
            }
            #pragma unroll
            for (int mt = 0; mt < 4; ++mt)
                #pragma unroll
                for (int nb = 0; nb < 2; ++nb)
                    acc[half * 4 + mt][nb] =
                        __builtin_amdgcn_mfma_f32_16x16x32_bf16(af[mt], bb[slot][nb].v,
                                                                acc[half * 4 + mt][nb], 0, 0, 0);
        }
        if (ksub < 4) loadB(ksub + 4, bb[slot]);   // refill ring after use
    }

    // ---- epilogue: in-register GLU -> per-wave LDS [64][36] -> coalesced out
    __syncthreads();
    float* sEp = (float*)smem + wv * 2304;   // 64*36 floats per wave
    #pragma unroll
    for (int mt = 0; mt < 4; ++mt) {
        int r0 = mt * 16 + hi * 4;
        float4 ba = *(const float4*)&bo[m0 + wm * 64 + r0];
        float4 bg = *(const float4*)&bo[256 + m0 + wm * 64 + r0];
        #pragma unroll
        for (int nb = 0; nb < 2; ++nb) {
            #pragma unroll
            for (int rr = 0; rr < 4; ++rr) {
                float a = acc[mt][nb][rr]     + ((const float*)&ba)[rr];
                float g = acc[4 + mt][nb][rr] + ((const float*)&bg)[rr];
                sEp[(r0 + rr) * 36 + nb * 16 + ln15] = a / (1.0f + __expf(-g));
            }
        }
    }
    __syncthreads();
    {
        const int rl = lane >> 3;
        const int c4 = (lane & 7) * 4;
        float* obase = out + ((size_t)(b * 256 + m0 + wm * 64)) * 4096 + l0 + wn * 32;
        #pragma unroll
        for (int ps = 0; ps < 8; ++ps) {
            int row = ps * 8 + rl;
            float4 v = *(const float4*)&sEp[row * 36 + c4];
            *(float4*)&obase[(size_t)row * 4096 + c4] = v;
        }
    }
}

extern "C" void kernel_launch(void* const* d_in, const int* in_sizes, int n_in,
                              void* d_out, int out_size, void* d_ws, size_t ws_size,
                              hipStream_t stream) {
    (void)in_sizes; (void)n_in; (void)out_size;
    const float* hs     = (const float*)d_in[0];
    const float* log_dt = (const float*)d_in[1];
    const float* logA   = (const float*)d_in[2];
    const float* Aim    = (const float*)d_in[3];
    const float* Cre    = (const float*)d_in[4];
    const float* Cim    = (const float*)d_in[5];
    const float* Dp     = (const float*)d_in[6];
    const float* Wout   = (const float*)d_in[7];
    const float* bout   = (const float*)d_in[8];
    float* out          = (float*)d_out;

    unsigned short* G   = (unsigned short*)d_ws;                           // 16 MB
    unsigned short* MAT = (unsigned short*)((char*)d_ws + 16777216);       // 6.29 MB
    unsigned short* W2  = (unsigned short*)((char*)d_ws + 23068672);       // 256 KB

    if (ws_size < (size_t)23330816) return;

    prep_kernel<<<dim3(384), dim3(256), 0, stream>>>(
        log_dt, logA, Aim, Cre, Cim, Dp, Wout, MAT, W2);
    s4_mfma_kernel<<<dim3(512), dim3(256), 0, stream>>>(
        hs, log_dt, logA, Aim, MAT, G);
    glu_gemm_kernel<<<dim3(64, 2, 8), dim3(256), 0, stream>>>(
        G, W2, bout, out);
}